// Round 6
// baseline (672.427 us; speedup 1.0000x reference)
//
#include <hip/hip_runtime.h>
#include <hip/hip_bf16.h>

// Bahdanau additive attention, MI355X. B=32, S=2048, E=D=1024. M = B*S = 65536.
// scores[m] = v . tanh(enc[m,:] @ w1 + qq[b]),  qq[b] = dec[b] @ w2 + b2 + b1
// (bv dropped: softmax-invariant). attn = softmax_s(scores); context[b] = attn[b,:] @ enc[b,:,:]
//
// Round-6 GEMM: single-barrier double-buffered K-loop (64KB LDS).
//   iter k: issue B-DMA(k+1 -> alt) + A fp32 loads(k+1) FIRST,
//           ds_read+MFMA(k) hides their latency,
//           then convert+ds_write A(k+1 -> alt) (vmcnt wait ~0),
//           one __syncthreads().
// This removes the naked A-load latency window that made round-5's
// two-barrier loop 333 us (vs 215 us for the pure-DMA r3 variant).
// LDS image per 128x64 bf16 tile: rows of 128B = 8 chunks of 16B, logical
// chunk c stored at c ^ (row & 7) — verified conflict-free rounds 2-5
// (SQ_LDS_BANK_CONFLICT = 0). w1 pre-packed in this order -> B stages via
// global_load_lds width-16 DMA.

typedef __attribute__((ext_vector_type(8))) short short8;   // 8 bf16 (4 VGPRs)
typedef __attribute__((ext_vector_type(4))) float f32x4;    // MFMA acc

#define M_TOTAL 65536
#define KDIM    1024
#define KT_N    16          // KDIM / 64

// pack two fp32 -> two bf16 (round-half-up) in one dword: 2 adds + 1 v_perm
static __device__ inline unsigned int pk2h(float a, float b) {
    unsigned int ua = __builtin_bit_cast(unsigned int, a) + 0x8000u;
    unsigned int ub = __builtin_bit_cast(unsigned int, b) + 0x8000u;
    return __builtin_amdgcn_perm(ub, ua, 0x07060302u);
}

static __device__ inline void async_copy16(const void* g, void* l) {
    __builtin_amdgcn_global_load_lds(
        (const __attribute__((address_space(1))) unsigned int*)g,
        (__attribute__((address_space(3))) unsigned int*)l, 16, 0, 0);
}

// ---- w1 [d][e] fp32 -> w1p bf16, BK=64 tiled+swizzled image order ----
__global__ void pack_w1(const float* __restrict__ w1, unsigned short* __restrict__ w1p) {
    __shared__ float tile[32][33];
    const int tx = threadIdx.x, ty = threadIdx.y;
    tile[ty][tx] = w1[(blockIdx.y * 32 + ty) * 1024 + blockIdx.x * 32 + tx];
    __syncthreads();
    const int eo = blockIdx.x * 32 + ty;   // n-dim
    const int dq = blockIdx.y * 32 + tx;   // k-dim
    const unsigned int u = __builtin_bit_cast(unsigned int, tile[tx][ty]) + 0x8000u;
    const unsigned short us = (unsigned short)(u >> 16);
    const int nt = eo >> 7, r = eo & 127;
    const int kc = dq >> 6, c = (dq >> 3) & 7, j = dq & 7;
    const int cs = c ^ (r & 7);
    w1p[(((size_t)(nt * 16 + kc)) << 13) + (r << 6) + (cs << 3) + j] = us;
}

// ---- qq[b][e] += partial of b1+b2 + dec[b]@w2, split-k x4 ----
__global__ __launch_bounds__(256) void qq_kern(const float* __restrict__ dec,
                                               const float* __restrict__ w2,
                                               const float* __restrict__ b1,
                                               const float* __restrict__ b2,
                                               float* __restrict__ qq) {
    const int b = blockIdx.y;
    const int e = blockIdx.x * 256 + threadIdx.x;
    const int d0 = blockIdx.z * 256;
    const float* db = dec + b * 1024;
    float acc = (blockIdx.z == 0) ? (b1[e] + b2[e]) : 0.f;
#pragma unroll 8
    for (int d = d0; d < d0 + 256; d++)
        acc = fmaf(db[d], w2[d * 1024 + e], acc);
    atomicAdd(&qq[b * 1024 + e], acc);
}

// ---- epilogue: tanh(C + qq)*v, quad butterfly, atomic into scores ----
static __device__ inline void score_epilogue(f32x4 acc[4][4], const float* qqb,
                                             const float* vvec, float* scores,
                                             int m0, int n0, int wm, int wn,
                                             int quad, int lc) {
    const int nb = n0 + wn * 64 + lc;
    float qn[4], vn[4];
#pragma unroll
    for (int ni = 0; ni < 4; ni++) {
        qn[ni] = qqb[nb + ni * 16];
        vn[ni] = vvec[nb + ni * 16];
    }
    float red[16];
#pragma unroll
    for (int mi = 0; mi < 4; mi++) {
#pragma unroll
        for (int r = 0; r < 4; r++) {
            float ssum = 0.f;
#pragma unroll
            for (int ni = 0; ni < 4; ni++) {
                float x = acc[mi][ni][r] + qn[ni];
                float e = __expf(2.0f * x);          // overflow-safe tanh
                float th = 1.0f - 2.0f / (e + 1.0f);
                ssum = fmaf(th, vn[ni], ssum);
            }
            float t = ssum;
            t += __shfl_xor(t, 1);
            t += __shfl_xor(t, 2);
            t += __shfl_xor(t, 4);
            t += __shfl_xor(t, 8);
            red[mi * 4 + r] = t;
        }
    }
    float myv = red[0];
#pragma unroll
    for (int i = 1; i < 16; i++)
        if (lc == i) myv = red[i];
    atomicAdd(scores + m0 + wm * 64 + (lc >> 2) * 16 + quad * 4 + (lc & 3), myv);
}

// ---- fused GEMM, BK=64, double-buffered, single barrier per iter ----
__global__ __launch_bounds__(256) void score_gemm(const float* __restrict__ enc,
                                                  const unsigned short* __restrict__ w1p,
                                                  const float* __restrict__ qq,
                                                  const float* __restrict__ vvec,
                                                  float* __restrict__ scores) {
    __shared__ __align__(16) unsigned short As[2][128 * 64];   // 2 x 16KB
    __shared__ __align__(16) unsigned short Bs[2][128 * 64];   // 2 x 16KB

    const int g = blockIdx.x;                   // 0..4095, XCD swizzle:
    const int mtile = (g & 7) * 64 + (g >> 6);  // 8 n-tiles of an m-strip
    const int ntile = (g >> 3) & 7;             // land on one XCD
    const int m0 = mtile * 128;
    const int b = m0 >> 11;

    const int tid = threadIdx.x;
    const int wid = tid >> 6;
    const int lane = tid & 63;
    const int wm = wid >> 1, wn = wid & 1;
    const int quad = lane >> 4, lc = lane & 15;
    const int swz = lc & 7;                     // row&7 for rows i*16+lc
    const int fc0 = ((quad ^ swz) << 3);        // khalf 0 chunk offset (elems)
    const int fc1 = (((4 + quad) ^ swz) << 3);  // khalf 1

    // A staging: rows r = sr0 + 32j (j=0..3), logical chunk sc = tid&7.
    // Per 8 lanes: one full 256B fp32 row-segment (coalesced).
    const int sr0 = tid >> 3;
    const int sc = tid & 7;

    f32x4 acc[4][4];
#pragma unroll
    for (int mi = 0; mi < 4; mi++)
#pragma unroll
        for (int ni = 0; ni < 4; ni++)
            acc[mi][ni] = (f32x4){0.f, 0.f, 0.f, 0.f};

    const unsigned short* bbase = w1p + ((size_t)ntile << 17) + (wid << 11) + (lane << 3);
    float4 fv[8];

    // --- staging helpers ---
    auto issueB = [&](int kt, int pb) {
        const unsigned short* bsrc = bbase + ((size_t)kt << 13);
        unsigned short* bdst = &Bs[pb][wid << 11];
        async_copy16(bsrc, bdst);
        async_copy16(bsrc + 512, bdst + 512);
        async_copy16(bsrc + 1024, bdst + 1024);
        async_copy16(bsrc + 1536, bdst + 1536);
    };
    auto loadA = [&](int kt) {
#pragma unroll
        for (int j = 0; j < 4; j++) {
            const float* src = enc + (size_t)(m0 + sr0 + 32 * j) * 1024 + kt * 64 + sc * 8;
            fv[2 * j]     = *reinterpret_cast<const float4*>(src);
            fv[2 * j + 1] = *reinterpret_cast<const float4*>(src + 4);
        }
    };
    auto commitA = [&](int pb) {
#pragma unroll
        for (int j = 0; j < 4; j++) {
            const int r = sr0 + 32 * j;
            uint4 w;
            w.x = pk2h(fv[2 * j].x, fv[2 * j].y);
            w.y = pk2h(fv[2 * j].z, fv[2 * j].w);
            w.z = pk2h(fv[2 * j + 1].x, fv[2 * j + 1].y);
            w.w = pk2h(fv[2 * j + 1].z, fv[2 * j + 1].w);
            *reinterpret_cast<uint4*>(&As[pb][(r << 6) + ((sc ^ (r & 7)) << 3)]) = w;
        }
    };
    auto compute = [&](int pb) {
        short8 af[4], bf[4];
#pragma unroll
        for (int i = 0; i < 4; i++) {
            af[i] = *reinterpret_cast<const short8*>(&As[pb][((wm * 64 + i * 16 + lc) << 6) + fc0]);
            bf[i] = *reinterpret_cast<const short8*>(&Bs[pb][((wn * 64 + i * 16 + lc) << 6) + fc0]);
        }
#pragma unroll
        for (int mi = 0; mi < 4; mi++)
#pragma unroll
            for (int ni = 0; ni < 4; ni++)
                acc[mi][ni] = __builtin_amdgcn_mfma_f32_16x16x32_bf16(af[mi], bf[ni], acc[mi][ni], 0, 0, 0);
#pragma unroll
        for (int i = 0; i < 4; i++) {
            af[i] = *reinterpret_cast<const short8*>(&As[pb][((wm * 64 + i * 16 + lc) << 6) + fc1]);
            bf[i] = *reinterpret_cast<const short8*>(&Bs[pb][((wn * 64 + i * 16 + lc) << 6) + fc1]);
        }
#pragma unroll
        for (int mi = 0; mi < 4; mi++)
#pragma unroll
            for (int ni = 0; ni < 4; ni++)
                acc[mi][ni] = __builtin_amdgcn_mfma_f32_16x16x32_bf16(af[mi], bf[ni], acc[mi][ni], 0, 0, 0);
    };

    // prologue: stage kt=0 into buffer 0 (one-time exposed latency)
    issueB(0, 0);
    loadA(0);
    commitA(0);
    __syncthreads();

#pragma unroll 2
    for (int kt = 0; kt < KT_N; kt++) {
        const int p = kt & 1;
        if (kt + 1 < KT_N) {
            issueB(kt + 1, p ^ 1);   // async: lands in alt buffer
            loadA(kt + 1);           // fp32 loads in flight across compute()
        }
        compute(p);                  // ds_read + 32 MFMA hides the latency
        if (kt + 1 < KT_N)
            commitA(p ^ 1);          // vmcnt wait ~0 here; writes to alt buffer
        __syncthreads();             // single barrier: everything already drained
    }

    score_epilogue(acc, qq + b * 1024, vvec, scores, m0, ntile * 128, wm, wn, quad, lc);
}

// ---- softmax over s (2048) per batch ----
__global__ __launch_bounds__(256) void softmax_kern(const float* __restrict__ scores,
                                                    float* __restrict__ attn) {
    const int b = blockIdx.x;
    const int tid = threadIdx.x;
    const int wid = tid >> 6, lane = tid & 63;
    const float* s = scores + b * 2048;
    float x[8];
    float m = -1e30f;
#pragma unroll
    for (int i = 0; i < 8; i++) {
        x[i] = s[tid + i * 256];
        m = fmaxf(m, x[i]);
    }
    for (int off = 1; off < 64; off <<= 1) m = fmaxf(m, __shfl_xor(m, off));
    __shared__ float redm[4];
    if (lane == 0) redm[wid] = m;
    __syncthreads();
    m = fmaxf(fmaxf(redm[0], redm[1]), fmaxf(redm[2], redm[3]));
    float sum = 0.f;
#pragma unroll
    for (int i = 0; i < 8; i++) {
        x[i] = __expf(x[i] - m);
        sum += x[i];
    }
    for (int off = 1; off < 64; off <<= 1) sum += __shfl_xor(sum, off);
    __shared__ float reds[4];
    if (lane == 0) reds[wid] = sum;
    __syncthreads();
    sum = reds[0] + reds[1] + reds[2] + reds[3];
    const float inv = 1.0f / sum;
#pragma unroll
    for (int i = 0; i < 8; i++) attn[b * 2048 + tid + i * 256] = x[i] * inv;
}

// ---- context[b][e] = sum_s attn[b][s] * enc[b][s][e] ----
__global__ __launch_bounds__(256) void ctx_kern(const float* __restrict__ attn,
                                                const float* __restrict__ enc,
                                                float* __restrict__ out) {
    const int b = blockIdx.y;
    const int sc = blockIdx.x;    // 32 chunks x 64 s
    const int tid = threadIdx.x;
    const float* ab = attn + b * 2048 + sc * 64;
    const float* eb = enc + ((size_t)b * 2048 + sc * 64) * 1024 + tid * 4;
    float4 acc = {0.f, 0.f, 0.f, 0.f};
#pragma unroll 16
    for (int s = 0; s < 64; s++) {
        float w = ab[s];
        float4 ev = *reinterpret_cast<const float4*>(eb + (size_t)s * 1024);
        acc.x = fmaf(w, ev.x, acc.x);
        acc.y = fmaf(w, ev.y, acc.y);
        acc.z = fmaf(w, ev.z, acc.z);
        acc.w = fmaf(w, ev.w, acc.w);
    }
    float* op = out + b * 1024 + tid * 4;
    atomicAdd(op + 0, acc.x);
    atomicAdd(op + 1, acc.y);
    atomicAdd(op + 2, acc.z);
    atomicAdd(op + 3, acc.w);
}

extern "C" void kernel_launch(void* const* d_in, const int* in_sizes, int n_in,
                              void* d_out, int out_size, void* d_ws, size_t ws_size,
                              hipStream_t stream) {
    const float* enc = (const float*)d_in[0];  // 32*2048*1024
    const float* dec = (const float*)d_in[1];  // 32*1*1024
    const float* w1  = (const float*)d_in[2];  // 1024*1024
    const float* b1  = (const float*)d_in[3];  // 1024
    const float* w2  = (const float*)d_in[4];  // 1024*1024
    const float* b2  = (const float*)d_in[5];  // 1024
    const float* v   = (const float*)d_in[6];  // 1024
    // d_in[7] = bv, softmax-invariant, unused
    float* out = (float*)d_out;                // 32*1024

    char* ws = (char*)d_ws;
    unsigned short* w1p = (unsigned short*)ws;                 // 2 MB
    float* qq     = (float*)(ws + (2u << 20));                 // 128 KB
    float* scores = (float*)(ws + (2u << 20) + (128u << 10));  // 256 KB
    float* attn   = scores + M_TOTAL;                          // 256 KB
    // total ws need: ~2.65 MB (small footprint keeps enc warm in L3)

    hipMemsetAsync(qq, 0, (128u << 10) + M_TOTAL * sizeof(float), stream);
    hipMemsetAsync(out, 0, 32 * 1024 * sizeof(float), stream);

    pack_w1<<<dim3(32, 32), dim3(32, 32), 0, stream>>>(w1, w1p);
    qq_kern<<<dim3(4, 32, 4), 256, 0, stream>>>(dec, w2, b1, b2, qq);
    score_gemm<<<4096, 256, 0, stream>>>(enc, w1p, qq, v, scores);
    softmax_kern<<<32, 256, 0, stream>>>(scores, attn);
    ctx_kern<<<dim3(32, 32), 256, 0, stream>>>(attn, enc, out);
}